// Round 15
// baseline (118.356 us; speedup 1.0000x reference)
//
#include <hip/hip_runtime.h>
#include <math.h>

#define NBULK 62

typedef __attribute__((ext_vector_type(8))) short bf8_t;    // 8 x bf16
typedef __attribute__((ext_vector_type(4))) float f4_t;     // 4 x fp32

#define MFMA16(a, b, c) __builtin_amdgcn_mfma_f32_16x16x32_bf16((a), (b), (c), 0, 0, 0)

__device__ __forceinline__ unsigned short f2bf(float f) {
    unsigned int u = __float_as_uint(f);
    return (unsigned short)((u + 0x7FFFu + ((u >> 16) & 1u)) >> 16);
}
__device__ __forceinline__ float bf2f(unsigned short h) {
    return __uint_as_float(((unsigned int)h) << 16);
}
// pack 2 f32 -> 2 bf16 in one dword (RNE)
__device__ __forceinline__ unsigned cvtpk(float lo, float hi) {
    unsigned r;
    asm("v_cvt_pk_bf16_f32 %0, %1, %2" : "=v"(r) : "v"(lo), "v"(hi));
    return r;
}

// ---- ws layout ----
// floats: [0]=psisum [1]=lsf [2]=lsb [3]=spare ; E_fwd @f1024, E_bwd @f6144
// bytes:  NFf (62*16KB) @45056 ; NFb @1060864 ; PFf (15*32KB) @2097152 ; PFb @2621440
#define WS_E_OFF   1024
#define WS_B_OFF   6144
#define WS_NFF_OFF 45056
#define WS_NFB_OFF 1060864
#define WS_PFF_OFF 2097152
#define WS_PFB_OFF 2621440

// ===== fragment layout (verified r5..r13, absmax 0) =====
// perm16(32ks+8q+jj) = 16*(2ks+(jj>>2)) + 4q + (jj&3)
// NFf frag (p*4+t)*2+ks, lane q*16+ln, hw jj: M_p[perm16(...)][t*16+ln]
// NFb frag:                                   M_p[t*16+ln][perm16(...)]
// branch stride = 8 frags = 8192 B.  PAIR tiles: same layout, 4 branches c=a*2+b:
// fwd P_c = M_{2u,a}*M_{2u+1,b} scattered in NFf map (update E''=P^T E P);
// bwd Q_c = M_{60-2u,a}*M_{61-2u,b} scattered in NFb map (update E''=Q E Q^T).
// Composition: fwd sites s,s+1: M_{s+1}^T M_s^T E M_s M_{s+1} = (M_s M_{s+1})^T E (..)
// bwd sites s,s-1: M_{s-1}(M_s E M_s^T)M_{s-1}^T = (M_{s-1} M_s) E (M_{s-1} M_s)^T

extern "C" __global__ __launch_bounds__(256)
void mps_precompute(const float* __restrict__ bulkG,
                    unsigned short* __restrict__ NFfG,
                    unsigned short* __restrict__ NFbG,
                    unsigned short* __restrict__ PFfG,
                    unsigned short* __restrict__ PFbG,
                    float* __restrict__ wsF)
{
    extern __shared__ char smemP[];   // 32768 B
    const int s = blockIdx.x, tid = threadIdx.x;
    if (s < 62) {
        // ===== per-site fragment tiles (r13 verbatim) =====
        unsigned short* Ff = (unsigned short*)smemP;   // 8192 ush
        unsigned short* Fb = Ff + 8192;                // 8192 ush
        if (s == 0 && tid == 0) {
            wsF[0] = 0.f; wsF[1] = 0.f; wsF[2] = 0.f; wsF[3] = 0.f;
        }
        const float4* src = (const float4*)(bulkG + (size_t)s * 8192);
        for (int c = 0; c < 8; ++c) {
            int idx = tid + c * 256;
            float4 v = src[idx];
            int f  = idx * 4;
            int kk = f >> 7;
            int p  = (f >> 6) & 1;
            int j0 = f & 63;
            float vals[4] = {v.x, v.y, v.z, v.w};
            int qf = (kk >> 2) & 3, rf = kk & 3, mf = kk >> 4;
            int ksf = mf >> 1, jjf = (mf & 1) * 4 + rf;
            int tb = kk >> 4, lnb = kk & 15;
            #pragma unroll
            for (int t2 = 0; t2 < 4; ++t2) {
                int j = j0 + t2;
                unsigned short b = f2bf(vals[t2]);
                int tf = j >> 4, lnf = j & 15;
                Ff[((p * 4 + tf) * 2 + ksf) * 512 + (qf * 16 + lnf) * 8 + jjf] = b;
                int qb = (j >> 2) & 3, rb = j & 3, mb = j >> 4;
                int ksb = mb >> 1, jjb = (mb & 1) * 4 + rb;
                Fb[((p * 4 + tb) * 2 + ksb) * 512 + (qb * 16 + lnb) * 8 + jjb] = b;
            }
        }
        __syncthreads();
        const uint4* ff4 = (const uint4*)Ff;
        const uint4* fb4 = (const uint4*)Fb;
        uint4* fg = (uint4*)(NFfG + (size_t)s * 8192);
        uint4* bg = (uint4*)(NFbG + (size_t)s * 8192);
        for (int c = 0; c < 4; ++c) {
            int idx = tid + c * 256;
            fg[idx] = ff4[idx];
            bg[idx] = fb4[idx];
        }
    } else {
        // ===== pair-product tiles (bf16 factors, f32 accumulate) =====
        int pb = s - 62;                         // 0..29
        bool pf = pb < 15;
        int u  = pf ? pb : pb - 15;
        int sA = pf ? 2 * u     : 60 - 2 * u;    // left factor
        int sB = pf ? 2 * u + 1 : 61 - 2 * u;    // right factor
        unsigned short* A16 = (unsigned short*)smemP;   // 8192 ush (16KB)
        unsigned short* B16 = A16 + 8192;               // 8192 ush
        unsigned short* Sc  = (unsigned short*)smemP;   // overlays both after sync
        {
            const float4* sa4 = (const float4*)(bulkG + (size_t)sA * 8192);
            const float4* sb4 = (const float4*)(bulkG + (size_t)sB * 8192);
            for (int c = 0; c < 8; ++c) {
                int i = tid + c * 256;
                float4 va = sa4[i], vb = sb4[i];
                A16[i * 4 + 0] = f2bf(va.x); A16[i * 4 + 1] = f2bf(va.y);
                A16[i * 4 + 2] = f2bf(va.z); A16[i * 4 + 3] = f2bf(va.w);
                B16[i * 4 + 0] = f2bf(vb.x); B16[i * 4 + 1] = f2bf(vb.y);
                B16[i * 4 + 2] = f2bf(vb.z); B16[i * 4 + 3] = f2bf(vb.w);
            }
        }
        __syncthreads();
        const int d = tid >> 2, iBase = (tid & 3) * 16;
        float acc[4][16];
        #pragma unroll
        for (int c = 0; c < 4; ++c)
            #pragma unroll
            for (int ii = 0; ii < 16; ++ii) acc[c][ii] = 0.f;
        for (int e = 0; e < 64; ++e) {
            float a0 = bf2f(A16[d * 128 + e]);        // M_{sA,0}[d][e]
            float a1 = bf2f(A16[d * 128 + 64 + e]);   // M_{sA,1}[d][e]
            const unsigned short* b0p = B16 + e * 128 + iBase;       // M_{sB,0}[e][i]
            const unsigned short* b1p = b0p + 64;                    // M_{sB,1}[e][i]
            #pragma unroll
            for (int ii = 0; ii < 16; ++ii) {
                float b0 = bf2f(b0p[ii]), b1 = bf2f(b1p[ii]);
                acc[0][ii] = fmaf(a0, b0, acc[0][ii]);   // c = a*2+b
                acc[1][ii] = fmaf(a0, b1, acc[1][ii]);
                acc[2][ii] = fmaf(a1, b0, acc[2][ii]);
                acc[3][ii] = fmaf(a1, b1, acc[3][ii]);
            }
        }
        __syncthreads();   // A16/B16 reads complete before Sc overlay
        #pragma unroll
        for (int c = 0; c < 4; ++c)
            #pragma unroll
            for (int ii = 0; ii < 16; ++ii) {
                int i = iBase + ii;
                unsigned short vbf = f2bf(acc[c][ii]);
                int idx;
                if (pf)    // NFf map: row d permuted, col i natural
                    idx = c * 4096 + ((i >> 4) * 2 + (d >> 5)) * 512
                        + ((((d >> 2) & 3) * 16 + (i & 15)) << 3)
                        + ((d >> 4) & 1) * 4 + (d & 3);
                else       // NFb map: row d natural, col i permuted
                    idx = c * 4096 + ((d >> 4) * 2 + (i >> 5)) * 512
                        + ((((i >> 2) & 3) * 16 + (d & 15)) << 3)
                        + ((i >> 4) & 1) * 4 + (i & 3);
                Sc[idx] = vbf;
            }
        __syncthreads();
        uint4* dst = (uint4*)((pf ? (char*)PFfG : (char*)PFbG) + (size_t)u * 32768);
        const uint4* src4 = (const uint4*)Sc;
        for (int c = 0; c < 8; ++c) {
            int i = tid + c * 256;
            dst[i] = src4[i];
        }
    }
}

// coalesced fragment fetch from GLOBAL: 16 x b128, lane-contiguous (psi only)
__device__ __forceinline__ void pfetch(uint4 (&F)[16], const char* tb, int l16)
{
    #pragma unroll
    for (int i = 0; i < 16; ++i)
        F[i] = *(const uint4*)(tb + i * 1024 + l16);
}

// ===== psi helpers: 16-sample in-register chain (zero LDS, zero barriers) =====
__device__ __forceinline__ void pstep(f4_t (&a)[2][4], const uint4 (&F)[16],
                                      const bf8_t (&B)[2])
{
    #pragma unroll
    for (int p = 0; p < 2; ++p)
        #pragma unroll
        for (int mt = 0; mt < 4; ++mt) { f4_t z = {0.f, 0.f, 0.f, 0.f}; a[p][mt] = z; }
    #pragma unroll
    for (int ks = 0; ks < 2; ++ks)
        #pragma unroll
        for (int p = 0; p < 2; ++p)
            #pragma unroll
            for (int mt = 0; mt < 4; ++mt)
                a[p][mt] = MFMA16(*(const bf8_t*)&F[(p * 4 + mt) * 2 + ks], B[ks], a[p][mt]);
}

__device__ __forceinline__ void ppack(bf8_t (&B)[2], const f4_t (&a)[2][4], bool takeB)
{
    #pragma unroll
    for (int ks = 0; ks < 2; ++ks) {
        unsigned w[4];
        #pragma unroll
        for (int d = 0; d < 4; ++d) {
            int mt = 2 * ks + (d >> 1), r = (d & 1) * 2;
            float x0 = takeB ? a[1][mt][r]     : a[0][mt][r];
            float x1 = takeB ? a[1][mt][r + 1] : a[0][mt][r + 1];
            w[d] = cvtpk(x0, x1);
        }
        uint4 u = {w[0], w[1], w[2], w[3]};
        B[ks] = *(const bf8_t*)&u;
    }
}

extern "C" __global__ __launch_bounds__(256, 1)
void mps_main(const int* __restrict__ cfgG, const float* __restrict__ leftG,
              const float* __restrict__ rightG, float* __restrict__ wsF,
              const unsigned short* __restrict__ NFfG,
              const unsigned short* __restrict__ NFbG,
              const unsigned short* __restrict__ PFfG,
              const unsigned short* __restrict__ PFbG)
{
    extern __shared__ char smem[];
    const int tid  = threadIdx.x;
    const int bid  = blockIdx.x;
    const int wv   = tid >> 6;
    const int lane = tid & 63;
    const int ln   = lane & 15, q = lane >> 4;
    const int l16  = lane * 16;

    if (bid >= 2) {
        // ===== psi (r13 verbatim, verified): 64 samples/block = 4 waves x 16 =====
        const char* NF = (const char*)NFfG;
        uint4 Fa[16], Fb[16];
        pfetch(Fa, NF, l16);
        pfetch(Fb, NF + 16384, l16);
        const int s0 = (bid - 2) * 64 + wv * 16;
        unsigned part = 0;
        {
            const int4* crow = (const int4*)(cfgG + (size_t)(s0 + ln) * 64 + q * 16);
            #pragma unroll
            for (int c = 0; c < 4; ++c) {
                int4 v = crow[c];
                part |= (unsigned)(v.x & 1) << (c * 4 + 0);
                part |= (unsigned)(v.y & 1) << (c * 4 + 1);
                part |= (unsigned)(v.z & 1) << (c * 4 + 2);
                part |= (unsigned)(v.w & 1) << (c * 4 + 3);
            }
        }
        unsigned pp   = __shfl_xor(part, 16);
        unsigned comb = (q & 1) ? (pp | (part << 16)) : (part | (pp << 16));
        unsigned selLo = __shfl(comb, ln);        // cfg cols 0..31
        unsigned selHi = __shfl(comb, ln + 32);   // cfg cols 32..63

        bf8_t B[2];
        {
            const float* lp = leftG + (selLo & 1u) * 64;
            #pragma unroll
            for (int ks = 0; ks < 2; ++ks) {
                unsigned w[4];
                #pragma unroll
                for (int d = 0; d < 4; ++d) {
                    int k0 = 16 * (2 * ks + (d >> 1)) + 4 * q + 2 * (d & 1);
                    w[d] = (unsigned)f2bf(lp[k0]) | ((unsigned)f2bf(lp[k0 + 1]) << 16);
                }
                uint4 u = {w[0], w[1], w[2], w[3]};
                B[ks] = *(const bf8_t*)&u;
            }
        }
        f4_t a[2][4];
        #define SELBIT(i) ((bool)((((i) < 32) ? (selLo >> (i)) : (selHi >> ((i) - 32))) & 1u))
        for (int t = 0; t < 60; t += 2) {
            pstep(a, Fa, B);
            pfetch(Fa, NF + (size_t)(t + 2) * 16384, l16);
            __builtin_amdgcn_sched_barrier(0);
            ppack(B, a, SELBIT(t + 1));
            pstep(a, Fb, B);
            pfetch(Fb, NF + (size_t)(t + 3) * 16384, l16);
            __builtin_amdgcn_sched_barrier(0);
            ppack(B, a, SELBIT(t + 2));
        }
        pstep(a, Fa, B);
        ppack(B, a, SELBIT(61));
        pstep(a, Fb, B);
        {
            bool tb2 = SELBIT(62);
            int selL = (int)(selHi >> 31) & 1;
            float psum = 0.f;
            #pragma unroll
            for (int mt = 0; mt < 4; ++mt)
                #pragma unroll
                for (int r = 0; r < 4; ++r) {
                    float v = tb2 ? a[1][mt][r] : a[0][mt][r];
                    psum = fmaf(v, rightG[(16 * mt + 4 * q + r) * 2 + selL], psum);
                }
            psum += __shfl_xor(psum, 16);
            psum += __shfl_xor(psum, 32);
            float lp2 = (lane < 16) ? logf(fmaxf(psum * psum, 1e-12f)) : 0.f;
            #pragma unroll
            for (int o = 1; o < 64; o <<= 1) lp2 += __shfl_xor(lp2, o);
            if (lane == 0) atomicAdd(&wsF[0], lp2);
        }
        #undef SELBIT
    } else {
        // ===== norm chain, SITE-PAIRED, ZERO staging LDS: fragments read directly
        //       from GLOBAL (16B/lane coalesced, the psi pattern, L2-hot).
        //       LDS = Xs exchange + wred only -> barriers order LDS-only state
        //       (no gload16, no vmcnt drain). 16 iterations: 15 pair-tiles
        //       (4 branches) + 1 singleton (2 branches). Inner math = r13's
        //       verified stage1->pack->stage2; branch index in ADDRESSES only. =====
        unsigned short* XsS = (unsigned short*)smem;     // [2][8][512] = 8192 ush
        float* wredS = (float*)(XsS + 8192);             // [2][4]

        const bool fwd = (bid == 0);
        const char* PF  = fwd ? (const char*)PFfG : (const char*)PFbG;
        const char* SNG = fwd ? ((const char*)NFfG + (size_t)30 * 16384)
                              : ((const char*)NFbG + (size_t)31 * 16384);
        // E0 A1-frags in-register: E0 = L^T L (fwd) / R R^T (bwd)  [r5 verbatim]
        bf8_t A1[4][2];
        {
            float li0[4], li1[4];
            #pragma unroll
            for (int mt = 0; mt < 4; ++mt) {
                int m = mt * 16 + ln;
                li0[mt] = fwd ? leftG[m]      : rightG[m * 2];
                li1[mt] = fwd ? leftG[64 + m] : rightG[m * 2 + 1];
            }
            #pragma unroll
            for (int ks = 0; ks < 2; ++ks) {
                float k0v[8], k1v[8];
                #pragma unroll
                for (int jj = 0; jj < 8; ++jj) {
                    int K = 16 * (2 * ks + (jj >> 2)) + 4 * q + (jj & 3);
                    k0v[jj] = fwd ? leftG[K]      : rightG[K * 2];
                    k1v[jj] = fwd ? leftG[64 + K] : rightG[K * 2 + 1];
                }
                #pragma unroll
                for (int mt = 0; mt < 4; ++mt) {
                    unsigned w[4];
                    #pragma unroll
                    for (int d = 0; d < 4; ++d) {
                        float x0 = li0[mt] * k0v[2 * d]     + li1[mt] * k1v[2 * d];
                        float x1 = li0[mt] * k0v[2 * d + 1] + li1[mt] * k1v[2 * d + 1];
                        w[d] = cvtpk(x0, x1);
                    }
                    uint4 u = {w[0], w[1], w[2], w[3]};
                    A1[mt][ks] = *(const bf8_t*)&u;
                }
            }
        }
        float lsum = 0.f;
        f4_t acc2s[2][4];
        for (int it = 0; it < 16; ++it) {
            __syncthreads();   // Xs[it&1], wred[(it-1)&1] visible (LDS-only drain)
            if (it > 0) {
                #pragma unroll
                for (int mt = 0; mt < 4; ++mt)
                    #pragma unroll
                    for (int ks = 0; ks < 2; ++ks)
                        A1[mt][ks] = *(const bf8_t*)&XsS[((it & 1) * 8 + mt * 2 + ks) * 512
                                                         + lane * 8];
            }
            const char* base = (it < 15) ? (PF + (size_t)it * 32768) : SNG;
            const int nb = (it < 15) ? 4 : 2;
            float inv = 1.f;
            if (it > 0) {
                const float* wp = wredS + ((it - 1) & 1) * 4;
                float mm = fmaxf(fmaxf(wp[0], wp[1]), fmaxf(wp[2], wp[3]));
                float sc = fmaxf(mm, 1e-30f);
                inv = 1.f / sc;
                lsum += logf(sc);
            }
            #pragma unroll
            for (int p = 0; p < 2; ++p)
                #pragma unroll
                for (int mt = 0; mt < 4; ++mt) {
                    f4_t z = {0.f, 0.f, 0.f, 0.f};
                    acc2s[p][mt] = z;
                }
            #pragma unroll
            for (int c = 0; c < 4; ++c) {
                if (c >= nb) continue;   // uniform scalar guard (it==15 singleton)
                const char* br = base + c * 8192;   // branch stride = 8 frags
                bf8_t B1c[2], A2c[4][2];
                #pragma unroll
                for (int ks = 0; ks < 2; ++ks)
                    B1c[ks] = *(const bf8_t*)(br + (wv * 2 + ks) * 1024 + l16);
                #pragma unroll
                for (int mt = 0; mt < 4; ++mt)
                    #pragma unroll
                    for (int ks = 0; ks < 2; ++ks)
                        A2c[mt][ks] = *(const bf8_t*)(br + (mt * 2 + ks) * 1024 + l16);
                // stage1: S_c[:, own cols] = E * P_c
                f4_t acc1[4];
                #pragma unroll
                for (int mt = 0; mt < 4; ++mt) { f4_t z = {0.f, 0.f, 0.f, 0.f}; acc1[mt] = z; }
                #pragma unroll
                for (int ks = 0; ks < 2; ++ks)
                    #pragma unroll
                    for (int mt = 0; mt < 4; ++mt)
                        acc1[mt] = MFMA16(A1[mt][ks], B1c[ks], acc1[mt]);
                // lane-local perm pack: acc1 (C layout) -> B2 (B-operand k-slots)
                bf8_t B2[2];
                #pragma unroll
                for (int ks = 0; ks < 2; ++ks) {
                    unsigned w[4];
                    #pragma unroll
                    for (int d = 0; d < 4; ++d) {
                        int mt = 2 * ks + (d >> 1), r = (d & 1) * 2;
                        w[d] = cvtpk(acc1[mt][r], acc1[mt][r + 1]);
                    }
                    uint4 u = {w[0], w[1], w[2], w[3]};
                    B2[ks] = *(const bf8_t*)&u;
                }
                // stage2: E' += P_c-side * S_c  (branch-parity split accumulator)
                #pragma unroll
                for (int ks = 0; ks < 2; ++ks)
                    #pragma unroll
                    for (int mt = 0; mt < 4; ++mt)
                        acc2s[c & 1][mt] = MFMA16(A2c[mt][ks], B2[ks], acc2s[c & 1][mt]);
            }
            // branch-sum + deferred rescale + running max
            float mx = 0.f;
            #pragma unroll
            for (int mt = 0; mt < 4; ++mt)
                #pragma unroll
                for (int r = 0; r < 4; ++r) {
                    float x = (acc2s[0][mt][r] + acc2s[1][mt][r]) * inv;
                    acc2s[0][mt][r] = x;
                    mx = fmaxf(mx, fabsf(x));
                }
            // pack own A1'-frags for next iter (E' symmetric -> lane-local), exchange
            #pragma unroll
            for (int ks = 0; ks < 2; ++ks) {
                unsigned w[4];
                #pragma unroll
                for (int d = 0; d < 4; ++d) {
                    int mt = 2 * ks + (d >> 1), r = (d & 1) * 2;
                    w[d] = cvtpk(acc2s[0][mt][r], acc2s[0][mt][r + 1]);
                }
                uint4 u = {w[0], w[1], w[2], w[3]};
                *(uint4*)&XsS[(((it + 1) & 1) * 8 + wv * 2 + ks) * 512 + lane * 8] = u;
            }
            #pragma unroll
            for (int o = 32; o > 0; o >>= 1) mx = fmaxf(mx, __shfl_xor(mx, o));
            if (lane == 0) wredS[(it & 1) * 4 + wv] = mx;
        }
        // write E (f32) for finalize  [r9 mapping]
        float* dst = wsF + (fwd ? WS_E_OFF : WS_B_OFF);
        #pragma unroll
        for (int mt = 0; mt < 4; ++mt)
            #pragma unroll
            for (int r = 0; r < 4; ++r)
                dst[(16 * mt + 4 * q + r) * 64 + wv * 16 + ln] = acc2s[0][mt][r];
        if (tid == 0) wsF[fwd ? 1 : 2] = lsum;
    }
}

extern "C" __global__ void mps_finalize(const float* __restrict__ wsF, float* __restrict__ out)
{
    const int lane = threadIdx.x;  // 64 threads
    const float* E  = wsF + WS_E_OFF;
    const float* Bm = wsF + WS_B_OFF;
    float a = 0.f;
    #pragma unroll 8
    for (int j = 0; j < 64; ++j)
        a = fmaf(E[j * 64 + lane], Bm[j * 64 + lane], a);   // coalesced
    #pragma unroll
    for (int off = 32; off > 0; off >>= 1)
        a += __shfl_down(a, off);
    if (lane == 0) {
        const float z = fmaxf(a, 1e-30f);
        const float log_z = logf(z) + wsF[1] + wsF[2];
        out[0] = log_z - wsF[0] * (1.0f / 8192.0f);
    }
}

extern "C" void kernel_launch(void* const* d_in, const int* in_sizes, int n_in,
                              void* d_out, int out_size, void* d_ws, size_t ws_size,
                              hipStream_t stream)
{
    const int*   cfg   = (const int*)d_in[0];    // (8192, 64) int32
    const float* left  = (const float*)d_in[1];  // (2, 64)
    const float* bulk  = (const float*)d_in[2];  // (62, 64, 2, 64)
    const float* right = (const float*)d_in[3];  // (64, 2)
    float* wsF = (float*)d_ws;
    unsigned short* NFf = (unsigned short*)((char*)d_ws + WS_NFF_OFF);
    unsigned short* NFb = (unsigned short*)((char*)d_ws + WS_NFB_OFF);
    unsigned short* PFf = (unsigned short*)((char*)d_ws + WS_PFF_OFF);
    unsigned short* PFb = (unsigned short*)((char*)d_ws + WS_PFB_OFF);

    // blocks 0..61 = per-site tiles; 62..91 = pair-product tiles (concurrent)
    mps_precompute<<<dim3(92), dim3(256), 32768, stream>>>(bulk, NFf, NFb, PFf, PFb, wsF);
    // blocks 0,1 = norm chains (paired, 16 iters, global frags, 16KB LDS);
    // 2..129 = psi (64 samples each: 4 waves x 16-sample in-register chains)
    mps_main<<<dim3(130), dim3(256), 16416, stream>>>(cfg, left, right, wsF,
                                                      NFf, NFb, PFf, PFb);
    mps_finalize<<<dim3(1), dim3(64), 0, stream>>>(wsF, (float*)d_out);
}

// Round 17
// 116.333 us; speedup vs baseline: 1.0174x; 1.0174x over previous
//
#include <hip/hip_runtime.h>
#include <math.h>

#define NBULK 62

typedef __attribute__((ext_vector_type(8))) short bf8_t;    // 8 x bf16
typedef __attribute__((ext_vector_type(4))) float f4_t;     // 4 x fp32

#define MFMA16(a, b, c) __builtin_amdgcn_mfma_f32_16x16x32_bf16((a), (b), (c), 0, 0, 0)

__device__ __forceinline__ unsigned short f2bf(float f) {
    unsigned int u = __float_as_uint(f);
    return (unsigned short)((u + 0x7FFFu + ((u >> 16) & 1u)) >> 16);
}
__device__ __forceinline__ float bf2f(unsigned short h) {
    return __uint_as_float(((unsigned int)h) << 16);
}
// pack 2 f32 -> 2 bf16 in one dword (RNE)
__device__ __forceinline__ unsigned cvtpk(float lo, float hi) {
    unsigned r;
    asm("v_cvt_pk_bf16_f32 %0, %1, %2" : "=v"(r) : "v"(lo), "v"(hi));
    return r;
}

// ---- ws layout ----
// floats: [0]=psisum [1]=lsf [2]=lsb [3]=spare ; E_fwd @f1024, E_bwd @f6144
// bytes:  NFf (62*16KB) @45056 ; NFb @1060864 ; PFf (15*32KB) @2097152 ; PFb @2621440
#define WS_E_OFF   1024
#define WS_B_OFF   6144
#define WS_NFF_OFF 45056
#define WS_NFB_OFF 1060864
#define WS_PFF_OFF 2097152
#define WS_PFB_OFF 2621440

// ===== fragment layout (verified r5..r15, absmax 0) =====
// perm16(32ks+8q+jj) = 16*(2ks+(jj>>2)) + 4q + (jj&3)
// NFf frag (p*4+t)*2+ks, lane q*16+ln, hw jj: M_p[perm16(...)][t*16+ln]
// NFb frag:                                   M_p[t*16+ln][perm16(...)]
// branch stride = 8 frags = 8192 B.  PAIR tiles (verified r15): 4 branches c=a*2+b:
// fwd P_c = M_{2u,a}*M_{2u+1,b} in NFf map; bwd Q_c = M_{60-2u,a}*M_{61-2u,b} in NFb map.

extern "C" __global__ __launch_bounds__(256)
void mps_precompute(const float* __restrict__ bulkG,
                    unsigned short* __restrict__ NFfG,
                    unsigned short* __restrict__ NFbG,
                    unsigned short* __restrict__ PFfG,
                    unsigned short* __restrict__ PFbG,
                    float* __restrict__ wsF)
{
    extern __shared__ char smemP[];   // 32768 B
    const int s = blockIdx.x, tid = threadIdx.x;
    if (s < 62) {
        // ===== per-site fragment tiles (r13 verbatim) =====
        unsigned short* Ff = (unsigned short*)smemP;   // 8192 ush
        unsigned short* Fb = Ff + 8192;                // 8192 ush
        if (s == 0 && tid == 0) {
            wsF[0] = 0.f; wsF[1] = 0.f; wsF[2] = 0.f; wsF[3] = 0.f;
        }
        const float4* src = (const float4*)(bulkG + (size_t)s * 8192);
        for (int c = 0; c < 8; ++c) {
            int idx = tid + c * 256;
            float4 v = src[idx];
            int f  = idx * 4;
            int kk = f >> 7;
            int p  = (f >> 6) & 1;
            int j0 = f & 63;
            float vals[4] = {v.x, v.y, v.z, v.w};
            int qf = (kk >> 2) & 3, rf = kk & 3, mf = kk >> 4;
            int ksf = mf >> 1, jjf = (mf & 1) * 4 + rf;
            int tb = kk >> 4, lnb = kk & 15;
            #pragma unroll
            for (int t2 = 0; t2 < 4; ++t2) {
                int j = j0 + t2;
                unsigned short b = f2bf(vals[t2]);
                int tf = j >> 4, lnf = j & 15;
                Ff[((p * 4 + tf) * 2 + ksf) * 512 + (qf * 16 + lnf) * 8 + jjf] = b;
                int qb = (j >> 2) & 3, rb = j & 3, mb = j >> 4;
                int ksb = mb >> 1, jjb = (mb & 1) * 4 + rb;
                Fb[((p * 4 + tb) * 2 + ksb) * 512 + (qb * 16 + lnb) * 8 + jjb] = b;
            }
        }
        __syncthreads();
        const uint4* ff4 = (const uint4*)Ff;
        const uint4* fb4 = (const uint4*)Fb;
        uint4* fg = (uint4*)(NFfG + (size_t)s * 8192);
        uint4* bg = (uint4*)(NFbG + (size_t)s * 8192);
        for (int c = 0; c < 4; ++c) {
            int idx = tid + c * 256;
            fg[idx] = ff4[idx];
            bg[idx] = fb4[idx];
        }
    } else {
        // ===== pair-product tiles (r15 verbatim, verified) =====
        int pb = s - 62;                         // 0..29
        bool pf = pb < 15;
        int u  = pf ? pb : pb - 15;
        int sA = pf ? 2 * u     : 60 - 2 * u;    // left factor
        int sB = pf ? 2 * u + 1 : 61 - 2 * u;    // right factor
        unsigned short* A16 = (unsigned short*)smemP;   // 8192 ush (16KB)
        unsigned short* B16 = A16 + 8192;               // 8192 ush
        unsigned short* Sc  = (unsigned short*)smemP;   // overlays both after sync
        {
            const float4* sa4 = (const float4*)(bulkG + (size_t)sA * 8192);
            const float4* sb4 = (const float4*)(bulkG + (size_t)sB * 8192);
            for (int c = 0; c < 8; ++c) {
                int i = tid + c * 256;
                float4 va = sa4[i], vb = sb4[i];
                A16[i * 4 + 0] = f2bf(va.x); A16[i * 4 + 1] = f2bf(va.y);
                A16[i * 4 + 2] = f2bf(va.z); A16[i * 4 + 3] = f2bf(va.w);
                B16[i * 4 + 0] = f2bf(vb.x); B16[i * 4 + 1] = f2bf(vb.y);
                B16[i * 4 + 2] = f2bf(vb.z); B16[i * 4 + 3] = f2bf(vb.w);
            }
        }
        __syncthreads();
        const int d = tid >> 2, iBase = (tid & 3) * 16;
        float acc[4][16];
        #pragma unroll
        for (int c = 0; c < 4; ++c)
            #pragma unroll
            for (int ii = 0; ii < 16; ++ii) acc[c][ii] = 0.f;
        for (int e = 0; e < 64; ++e) {
            float a0 = bf2f(A16[d * 128 + e]);        // M_{sA,0}[d][e]
            float a1 = bf2f(A16[d * 128 + 64 + e]);   // M_{sA,1}[d][e]
            const unsigned short* b0p = B16 + e * 128 + iBase;       // M_{sB,0}[e][i]
            const unsigned short* b1p = b0p + 64;                    // M_{sB,1}[e][i]
            #pragma unroll
            for (int ii = 0; ii < 16; ++ii) {
                float b0 = bf2f(b0p[ii]), b1 = bf2f(b1p[ii]);
                acc[0][ii] = fmaf(a0, b0, acc[0][ii]);   // c = a*2+b
                acc[1][ii] = fmaf(a0, b1, acc[1][ii]);
                acc[2][ii] = fmaf(a1, b0, acc[2][ii]);
                acc[3][ii] = fmaf(a1, b1, acc[3][ii]);
            }
        }
        __syncthreads();   // A16/B16 reads complete before Sc overlay
        #pragma unroll
        for (int c = 0; c < 4; ++c)
            #pragma unroll
            for (int ii = 0; ii < 16; ++ii) {
                int i = iBase + ii;
                unsigned short vbf = f2bf(acc[c][ii]);
                int idx;
                if (pf)    // NFf map: row d permuted, col i natural
                    idx = c * 4096 + ((i >> 4) * 2 + (d >> 5)) * 512
                        + ((((d >> 2) & 3) * 16 + (i & 15)) << 3)
                        + ((d >> 4) & 1) * 4 + (d & 3);
                else       // NFb map: row d natural, col i permuted
                    idx = c * 4096 + ((d >> 4) * 2 + (i >> 5)) * 512
                        + ((((i >> 2) & 3) * 16 + (d & 15)) << 3)
                        + ((i >> 4) & 1) * 4 + (i & 3);
                Sc[idx] = vbf;
            }
        __syncthreads();
        uint4* dst = (uint4*)((pf ? (char*)PFfG : (char*)PFbG) + (size_t)u * 32768);
        const uint4* src4 = (const uint4*)Sc;
        for (int c = 0; c < 8; ++c) {
            int i = tid + c * 256;
            dst[i] = src4[i];
        }
    }
}

// coalesced fragment fetch from GLOBAL: 16 x b128, lane-contiguous (psi only)
__device__ __forceinline__ void pfetch(uint4 (&F)[16], const char* tb, int l16)
{
    #pragma unroll
    for (int i = 0; i < 16; ++i)
        F[i] = *(const uint4*)(tb + i * 1024 + l16);
}

// ===== psi helpers (r13-verified math) =====
__device__ __forceinline__ void pstep(f4_t (&a)[2][4], const uint4 (&F)[16],
                                      const bf8_t (&B)[2])
{
    #pragma unroll
    for (int p = 0; p < 2; ++p)
        #pragma unroll
        for (int mt = 0; mt < 4; ++mt) { f4_t z = {0.f, 0.f, 0.f, 0.f}; a[p][mt] = z; }
    #pragma unroll
    for (int ks = 0; ks < 2; ++ks)
        #pragma unroll
        for (int p = 0; p < 2; ++p)
            #pragma unroll
            for (int mt = 0; mt < 4; ++mt)
                a[p][mt] = MFMA16(*(const bf8_t*)&F[(p * 4 + mt) * 2 + ks], B[ks], a[p][mt]);
}

__device__ __forceinline__ void ppack(bf8_t (&B)[2], const f4_t (&a)[2][4], bool takeB)
{
    #pragma unroll
    for (int ks = 0; ks < 2; ++ks) {
        unsigned w[4];
        #pragma unroll
        for (int d = 0; d < 4; ++d) {
            int mt = 2 * ks + (d >> 1), r = (d & 1) * 2;
            float x0 = takeB ? a[1][mt][r]     : a[0][mt][r];
            float x1 = takeB ? a[1][mt][r + 1] : a[0][mt][r + 1];
            w[d] = cvtpk(x0, x1);
        }
        uint4 u = {w[0], w[1], w[2], w[3]};
        B[ks] = *(const bf8_t*)&u;
    }
}

// cfg bit-pack for 16 samples (base..base+15), r13-verified pattern
__device__ __forceinline__ void psi_sel(const int* cfgG, int base, int ln, int q,
                                        unsigned& selLo, unsigned& selHi)
{
    unsigned part = 0;
    const int4* crow = (const int4*)(cfgG + (size_t)(base + ln) * 64 + q * 16);
    #pragma unroll
    for (int c = 0; c < 4; ++c) {
        int4 v = crow[c];
        part |= (unsigned)(v.x & 1) << (c * 4 + 0);
        part |= (unsigned)(v.y & 1) << (c * 4 + 1);
        part |= (unsigned)(v.z & 1) << (c * 4 + 2);
        part |= (unsigned)(v.w & 1) << (c * 4 + 3);
    }
    unsigned pp   = __shfl_xor(part, 16);
    unsigned comb = (q & 1) ? (pp | (part << 16)) : (part | (pp << 16));
    selLo = __shfl(comb, ln);        // cfg cols 0..31
    selHi = __shfl(comb, ln + 32);   // cfg cols 32..63
}

// env0 = left[cfg[:,0]] straight into B-frags (perm16 baked in)
__device__ __forceinline__ void psi_env0(bf8_t (&B)[2], const float* lp, int q)
{
    #pragma unroll
    for (int ks = 0; ks < 2; ++ks) {
        unsigned w[4];
        #pragma unroll
        for (int d = 0; d < 4; ++d) {
            int k0 = 16 * (2 * ks + (d >> 1)) + 4 * q + 2 * (d & 1);
            w[d] = (unsigned)f2bf(lp[k0]) | ((unsigned)f2bf(lp[k0 + 1]) << 16);
        }
        uint4 u = {w[0], w[1], w[2], w[3]};
        B[ks] = *(const bf8_t*)&u;
    }
}

__device__ __forceinline__ float psi_dot(const f4_t (&a)[2][4], bool tb2,
                                         const float* rightG, int selL, int q)
{
    float psum = 0.f;
    #pragma unroll
    for (int mt = 0; mt < 4; ++mt)
        #pragma unroll
        for (int r = 0; r < 4; ++r) {
            float v = tb2 ? a[1][mt][r] : a[0][mt][r];
            psum = fmaf(v, rightG[(16 * mt + 4 * q + r) * 2 + selL], psum);
        }
    psum += __shfl_xor(psum, 16);   // sum the 4 q-lane partials
    psum += __shfl_xor(psum, 32);
    return psum;
}

extern "C" __global__ __launch_bounds__(256, 1)
void mps_main(const int* __restrict__ cfgG, const float* __restrict__ leftG,
              const float* __restrict__ rightG, float* __restrict__ wsF,
              const unsigned short* __restrict__ NFfG,
              const unsigned short* __restrict__ NFbG,
              const unsigned short* __restrict__ PFfG,
              const unsigned short* __restrict__ PFbG)
{
    extern __shared__ char smem[];
    const int tid  = threadIdx.x;
    const int bid  = blockIdx.x;
    const int wv   = tid >> 6;
    const int lane = tid & 63;
    const int ln   = lane & 15, q = lane >> 4;
    const int l16  = lane * 16;

    if (bid >= 2) {
        // ===== psi: DUAL-CHAIN per wave (r4-verified pattern on the r13-verified
        //       MFMA16 chain): two independent 16-sample chains share Fa/Fb;
        //       the interleaved MFMA/pack streams hide each other's dependent
        //       latency in-wave (r15 showed the reg double-buffer never
        //       materializes, so in-wave ILP is the reliable mechanism).
        //       64 psi blocks x 4 waves x 32 samples. Zero LDS, zero barriers. =====
        const char* NF = (const char*)NFfG;
        uint4 Fa[16], Fb[16];
        pfetch(Fa, NF, l16);
        pfetch(Fb, NF + 16384, l16);
        const int s0 = (bid - 2) * 128 + wv * 32;   // chain0: s0+ln ; chain1: s0+16+ln
        unsigned sl0, sh0, sl1, sh1;
        psi_sel(cfgG, s0,      ln, q, sl0, sh0);
        psi_sel(cfgG, s0 + 16, ln, q, sl1, sh1);

        bf8_t B0[2], B1[2];
        psi_env0(B0, leftG + (sl0 & 1u) * 64, q);
        psi_env0(B1, leftG + (sl1 & 1u) * 64, q);

        f4_t a0[2][4], a1[2][4];
        #define SB0(i) ((bool)((((i) < 32) ? (sl0 >> (i)) : (sh0 >> ((i) - 32))) & 1u))
        #define SB1(i) ((bool)((((i) < 32) ? (sl1 >> (i)) : (sh1 >> ((i) - 32))) & 1u))
        for (int t = 0; t < 60; t += 2) {
            pstep(a0, Fa, B0);                               // two independent
            pstep(a1, Fa, B1);                               // MFMA streams
            pfetch(Fa, NF + (size_t)(t + 2) * 16384, l16);   // consumed at t+2
            __builtin_amdgcn_sched_barrier(0);               // pin: no sinking
            ppack(B0, a0, SB0(t + 1));
            ppack(B1, a1, SB1(t + 1));
            pstep(a0, Fb, B0);
            pstep(a1, Fb, B1);
            pfetch(Fb, NF + (size_t)(t + 3) * 16384, l16);   // consumed at t+3
            __builtin_amdgcn_sched_barrier(0);               // pin: no sinking
            ppack(B0, a0, SB0(t + 2));
            ppack(B1, a1, SB1(t + 2));
        }
        pstep(a0, Fa, B0);          // site 60
        pstep(a1, Fa, B1);
        ppack(B0, a0, SB0(61));
        ppack(B1, a1, SB1(61));
        pstep(a0, Fb, B0);          // site 61
        pstep(a1, Fb, B1);
        {   // final select (cfg col 62) + dot with right[:, cfg col 63]
            float p0 = psi_dot(a0, SB0(62), rightG, (int)(sh0 >> 31) & 1, q);
            float p1 = psi_dot(a1, SB1(62), rightG, (int)(sh1 >> 31) & 1, q);
            float lp2 = 0.f;
            if (lane < 16)
                lp2 = logf(fmaxf(p0 * p0, 1e-12f)) + logf(fmaxf(p1 * p1, 1e-12f));
            #pragma unroll
            for (int o = 1; o < 64; o <<= 1) lp2 += __shfl_xor(lp2, o);
            if (lane == 0) atomicAdd(&wsF[0], lp2);
        }
        #undef SB0
        #undef SB1
    } else {
        // ===== norm chain (r15 verbatim, verified): SITE-PAIRED, zero staging LDS,
        //       fragments direct from global (L2-hot), 16 iterations, 1 barrier/iter. =====
        unsigned short* XsS = (unsigned short*)smem;     // [2][8][512] = 8192 ush
        float* wredS = (float*)(XsS + 8192);             // [2][4]

        const bool fwd = (bid == 0);
        const char* PF  = fwd ? (const char*)PFfG : (const char*)PFbG;
        const char* SNG = fwd ? ((const char*)NFfG + (size_t)30 * 16384)
                              : ((const char*)NFbG + (size_t)31 * 16384);
        // E0 A1-frags in-register: E0 = L^T L (fwd) / R R^T (bwd)  [r5 verbatim]
        bf8_t A1[4][2];
        {
            float li0[4], li1[4];
            #pragma unroll
            for (int mt = 0; mt < 4; ++mt) {
                int m = mt * 16 + ln;
                li0[mt] = fwd ? leftG[m]      : rightG[m * 2];
                li1[mt] = fwd ? leftG[64 + m] : rightG[m * 2 + 1];
            }
            #pragma unroll
            for (int ks = 0; ks < 2; ++ks) {
                float k0v[8], k1v[8];
                #pragma unroll
                for (int jj = 0; jj < 8; ++jj) {
                    int K = 16 * (2 * ks + (jj >> 2)) + 4 * q + (jj & 3);
                    k0v[jj] = fwd ? leftG[K]      : rightG[K * 2];
                    k1v[jj] = fwd ? leftG[64 + K] : rightG[K * 2 + 1];
                }
                #pragma unroll
                for (int mt = 0; mt < 4; ++mt) {
                    unsigned w[4];
                    #pragma unroll
                    for (int d = 0; d < 4; ++d) {
                        float x0 = li0[mt] * k0v[2 * d]     + li1[mt] * k1v[2 * d];
                        float x1 = li0[mt] * k0v[2 * d + 1] + li1[mt] * k1v[2 * d + 1];
                        w[d] = cvtpk(x0, x1);
                    }
                    uint4 u = {w[0], w[1], w[2], w[3]};
                    A1[mt][ks] = *(const bf8_t*)&u;
                }
            }
        }
        float lsum = 0.f;
        f4_t acc2s[2][4];
        for (int it = 0; it < 16; ++it) {
            __syncthreads();   // Xs[it&1], wred[(it-1)&1] visible (LDS-only drain)
            if (it > 0) {
                #pragma unroll
                for (int mt = 0; mt < 4; ++mt)
                    #pragma unroll
                    for (int ks = 0; ks < 2; ++ks)
                        A1[mt][ks] = *(const bf8_t*)&XsS[((it & 1) * 8 + mt * 2 + ks) * 512
                                                         + lane * 8];
            }
            const char* base = (it < 15) ? (PF + (size_t)it * 32768) : SNG;
            const int nb = (it < 15) ? 4 : 2;
            float inv = 1.f;
            if (it > 0) {
                const float* wp = wredS + ((it - 1) & 1) * 4;
                float mm = fmaxf(fmaxf(wp[0], wp[1]), fmaxf(wp[2], wp[3]));
                float sc = fmaxf(mm, 1e-30f);
                inv = 1.f / sc;
                lsum += logf(sc);
            }
            #pragma unroll
            for (int p = 0; p < 2; ++p)
                #pragma unroll
                for (int mt = 0; mt < 4; ++mt) {
                    f4_t z = {0.f, 0.f, 0.f, 0.f};
                    acc2s[p][mt] = z;
                }
            #pragma unroll
            for (int c = 0; c < 4; ++c) {
                if (c >= nb) continue;   // uniform scalar guard (it==15 singleton)
                const char* br = base + c * 8192;   // branch stride = 8 frags
                bf8_t B1c[2], A2c[4][2];
                #pragma unroll
                for (int ks = 0; ks < 2; ++ks)
                    B1c[ks] = *(const bf8_t*)(br + (wv * 2 + ks) * 1024 + l16);
                #pragma unroll
                for (int mt = 0; mt < 4; ++mt)
                    #pragma unroll
                    for (int ks = 0; ks < 2; ++ks)
                        A2c[mt][ks] = *(const bf8_t*)(br + (mt * 2 + ks) * 1024 + l16);
                // stage1: S_c[:, own cols] = E * P_c
                f4_t acc1[4];
                #pragma unroll
                for (int mt = 0; mt < 4; ++mt) { f4_t z = {0.f, 0.f, 0.f, 0.f}; acc1[mt] = z; }
                #pragma unroll
                for (int ks = 0; ks < 2; ++ks)
                    #pragma unroll
                    for (int mt = 0; mt < 4; ++mt)
                        acc1[mt] = MFMA16(A1[mt][ks], B1c[ks], acc1[mt]);
                // lane-local perm pack: acc1 (C layout) -> B2 (B-operand k-slots)
                bf8_t B2[2];
                #pragma unroll
                for (int ks = 0; ks < 2; ++ks) {
                    unsigned w[4];
                    #pragma unroll
                    for (int d = 0; d < 4; ++d) {
                        int mt = 2 * ks + (d >> 1), r = (d & 1) * 2;
                        w[d] = cvtpk(acc1[mt][r], acc1[mt][r + 1]);
                    }
                    uint4 u = {w[0], w[1], w[2], w[3]};
                    B2[ks] = *(const bf8_t*)&u;
                }
                // stage2: E' += P_c-side * S_c  (branch-parity split accumulator)
                #pragma unroll
                for (int ks = 0; ks < 2; ++ks)
                    #pragma unroll
                    for (int mt = 0; mt < 4; ++mt)
                        acc2s[c & 1][mt] = MFMA16(A2c[mt][ks], B2[ks], acc2s[c & 1][mt]);
            }
            // branch-sum + deferred rescale + running max
            float mx = 0.f;
            #pragma unroll
            for (int mt = 0; mt < 4; ++mt)
                #pragma unroll
                for (int r = 0; r < 4; ++r) {
                    float x = (acc2s[0][mt][r] + acc2s[1][mt][r]) * inv;
                    acc2s[0][mt][r] = x;
                    mx = fmaxf(mx, fabsf(x));
                }
            // pack own A1'-frags for next iter (E' symmetric -> lane-local), exchange
            #pragma unroll
            for (int ks = 0; ks < 2; ++ks) {
                unsigned w[4];
                #pragma unroll
                for (int d = 0; d < 4; ++d) {
                    int mt = 2 * ks + (d >> 1), r = (d & 1) * 2;
                    w[d] = cvtpk(acc2s[0][mt][r], acc2s[0][mt][r + 1]);
                }
                uint4 u = {w[0], w[1], w[2], w[3]};
                *(uint4*)&XsS[(((it + 1) & 1) * 8 + wv * 2 + ks) * 512 + lane * 8] = u;
            }
            #pragma unroll
            for (int o = 32; o > 0; o >>= 1) mx = fmaxf(mx, __shfl_xor(mx, o));
            if (lane == 0) wredS[(it & 1) * 4 + wv] = mx;
        }
        // write E (f32) for finalize  [r9 mapping]
        float* dst = wsF + (fwd ? WS_E_OFF : WS_B_OFF);
        #pragma unroll
        for (int mt = 0; mt < 4; ++mt)
            #pragma unroll
            for (int r = 0; r < 4; ++r)
                dst[(16 * mt + 4 * q + r) * 64 + wv * 16 + ln] = acc2s[0][mt][r];
        if (tid == 0) wsF[fwd ? 1 : 2] = lsum;
    }
}

extern "C" __global__ void mps_finalize(const float* __restrict__ wsF, float* __restrict__ out)
{
    const int lane = threadIdx.x;  // 64 threads
    const float* E  = wsF + WS_E_OFF;
    const float* Bm = wsF + WS_B_OFF;
    float a = 0.f;
    #pragma unroll 8
    for (int j = 0; j < 64; ++j)
        a = fmaf(E[j * 64 + lane], Bm[j * 64 + lane], a);   // coalesced
    #pragma unroll
    for (int off = 32; off > 0; off >>= 1)
        a += __shfl_down(a, off);
    if (lane == 0) {
        const float z = fmaxf(a, 1e-30f);
        const float log_z = logf(z) + wsF[1] + wsF[2];
        out[0] = log_z - wsF[0] * (1.0f / 8192.0f);
    }
}

extern "C" void kernel_launch(void* const* d_in, const int* in_sizes, int n_in,
                              void* d_out, int out_size, void* d_ws, size_t ws_size,
                              hipStream_t stream)
{
    const int*   cfg   = (const int*)d_in[0];    // (8192, 64) int32
    const float* left  = (const float*)d_in[1];  // (2, 64)
    const float* bulk  = (const float*)d_in[2];  // (62, 64, 2, 64)
    const float* right = (const float*)d_in[3];  // (64, 2)
    float* wsF = (float*)d_ws;
    unsigned short* NFf = (unsigned short*)((char*)d_ws + WS_NFF_OFF);
    unsigned short* NFb = (unsigned short*)((char*)d_ws + WS_NFB_OFF);
    unsigned short* PFf = (unsigned short*)((char*)d_ws + WS_PFF_OFF);
    unsigned short* PFb = (unsigned short*)((char*)d_ws + WS_PFB_OFF);

    // blocks 0..61 = per-site tiles; 62..91 = pair-product tiles (concurrent)
    mps_precompute<<<dim3(92), dim3(256), 32768, stream>>>(bulk, NFf, NFb, PFf, PFb, wsF);
    // blocks 0,1 = norm chains (paired, 16 iters, global frags, 16KB LDS);
    // 2..65 = psi (128 samples each: 4 waves x 2 chains x 16 samples)
    mps_main<<<dim3(66), dim3(256), 16416, stream>>>(cfg, left, right, wsF,
                                                     NFf, NFb, PFf, PFb);
    mps_finalize<<<dim3(1), dim3(64), 0, stream>>>(wsF, (float*)d_out);
}